// Round 1
// baseline (2313.019 us; speedup 1.0000x reference)
//
#include <hip/hip_runtime.h>
#include <cstddef>

#define NCF 10

struct TFKeys { unsigned k[2 * NCF]; };

// Threefry-2x32, 20 rounds (JAX-compatible, partitionable semantics verified R1).
__host__ __device__ __forceinline__ void tf2x32(unsigned k0, unsigned k1,
                                                unsigned x0, unsigned x1,
                                                unsigned& o0, unsigned& o1) {
  const unsigned ks2 = k0 ^ k1 ^ 0x1BD11BDAu;
  x0 += k0; x1 += k1;
#define TF_R(r) x0 += x1; x1 = (x1 << (r)) | (x1 >> (32 - (r))); x1 ^= x0;
  TF_R(13) TF_R(15) TF_R(26) TF_R(6)
  x0 += k1;  x1 += ks2 + 1u;
  TF_R(17) TF_R(29) TF_R(16) TF_R(24)
  x0 += ks2; x1 += k0 + 2u;
  TF_R(13) TF_R(15) TF_R(26) TF_R(6)
  x0 += k0;  x1 += k1 + 3u;
  TF_R(17) TF_R(29) TF_R(16) TF_R(24)
  x0 += k1;  x1 += ks2 + 4u;
  TF_R(13) TF_R(15) TF_R(26) TF_R(6)
  x0 += ks2; x1 += k0 + 5u;
#undef TF_R
  o0 = x0; o1 = x1;
}

__device__ __forceinline__ float u01(unsigned bits) {
  return __uint_as_float((bits >> 9) | 0x3f800000u) - 1.0f;
}

// ---------------------------------------------------------------------------
// Kernel 1: HO[s][c] = b1[c] + sum_{k<256} obs[s][k] * W1[k][c]
// One sample per lane; weights via scalar (s_load) path, SGPR operand in FMA.
// 512 blocks x 256 threads = 131072 lanes.
// ---------------------------------------------------------------------------
__global__ __launch_bounds__(256, 2)
void hobs_kernel(const float* __restrict__ obs, const float* __restrict__ W1,
                 const float* __restrict__ b1, float* __restrict__ HO) {
  const int s = blockIdx.x * 256 + threadIdx.x;
  const float* orow = obs + (size_t)s * 256;

  float acc[128];
#pragma unroll
  for (int c = 0; c < 128; ++c) acc[c] = b1[c];

  // k blocked by 8; obs row slice in regs (static fields), weights uniform.
  for (int kb = 0; kb < 32; ++kb) {
    const float4 a0 = *(const float4*)(orow + kb * 8);
    const float4 a1 = *(const float4*)(orow + kb * 8 + 4);
    const float* wr = W1 + (size_t)kb * 8 * 128;
#pragma unroll
    for (int c = 0; c < 128; ++c) {
      float v = acc[c];
      v = fmaf(a0.x, wr[c],       v);
      v = fmaf(a0.y, wr[128 + c], v);
      v = fmaf(a0.z, wr[256 + c], v);
      v = fmaf(a0.w, wr[384 + c], v);
      v = fmaf(a1.x, wr[512 + c], v);
      v = fmaf(a1.y, wr[640 + c], v);
      v = fmaf(a1.z, wr[768 + c], v);
      v = fmaf(a1.w, wr[896 + c], v);
      acc[c] = v;
    }
  }

  float* drow = HO + (size_t)s * 128;
#pragma unroll
  for (int i = 0; i < 32; ++i)
    *(float4*)(drow + i * 4) =
        make_float4(acc[i * 4], acc[i * 4 + 1], acc[i * 4 + 2], acc[i * 4 + 3]);
}

// ---------------------------------------------------------------------------
// Kernel 2: one sample per lane, 12 passes. Weights always wave-uniform
// (scalar loads). Runtime-k-indexed activations live in a private per-thread
// LDS strip (68 floats, stride 272B = 17*16B -> conflict-free b128).
// Pass order: p=0 zeros, p=1..10 counterfactual RNG, p=11 with-actions (last,
// so pwith only briefly overlaps pacc in registers). Zero barriers.
// ---------------------------------------------------------------------------
__global__ __launch_bounds__(256, 2)
void infl2_kernel(const float* __restrict__ actions, const float* __restrict__ W1,
                  const float* __restrict__ W2, const float* __restrict__ b2,
                  const float* __restrict__ W3, const float* __restrict__ b3,
                  const float* __restrict__ HO, float* __restrict__ out,
                  TFKeys keys) {
  __shared__ float s_act[256 * 68];   // 68 KB: private strips, no sharing, no barriers
  const int t = threadIdx.x;
  const int s = blockIdx.x * 256 + t;
  float* strip = s_act + t * 68;
  const float* W1A   = W1 + 256 * 128;             // action rows of W1
  const float* horow = HO + (size_t)s * 128;

  float pacc[64];
#pragma unroll
  for (int c = 0; c < 64; ++c) pacc[c] = 0.f;
  float pw[64];                                    // live only in pass 11 + epilogue

  for (int p = 0; p < 12; ++p) {
    // ---- stage activations into private strip ----
    if (p >= 1 && p <= 10) {
      const unsigned k0 = keys.k[2 * (p - 1)];
      const unsigned k1 = keys.k[2 * (p - 1) + 1];
      const unsigned base = (unsigned)s * 64u;
      for (int eb = 0; eb < 16; ++eb) {            // rolled; regs statically indexed
        float v[4];
#pragma unroll
        for (int j = 0; j < 4; ++j) {
          unsigned o0, o1;
          tf2x32(k0, k1, 0u, base + (unsigned)(eb * 4 + j), o0, o1);
          v[j] = u01(o0 ^ o1);
        }
        *(float4*)(strip + eb * 4) = make_float4(v[0], v[1], v[2], v[3]);
      }
    } else if (p == 11) {
      const float4* arow = (const float4*)(actions + (size_t)s * 64);
      for (int eb = 0; eb < 16; ++eb)
        *(float4*)(strip + eb * 4) = arow[eb];
    }
    // p == 0: zero actions -> L1a skipped entirely

    float h2[64];
#pragma unroll
    for (int c = 0; c < 64; ++c) h2[c] = 0.f;

    for (int cb = 0; cb < 4; ++cb) {               // 32 h1-cols per block, rolled
      // ---- L1a: h1b = HO chunk (+ act @ W1A[:, cb*32..]) ----
      float h1b[32];
      {
        const float4* hsrc = (const float4*)(horow + cb * 32);
#pragma unroll
        for (int i = 0; i < 8; ++i) {
          const float4 hv = hsrc[i];
          h1b[i * 4 + 0] = hv.x; h1b[i * 4 + 1] = hv.y;
          h1b[i * 4 + 2] = hv.z; h1b[i * 4 + 3] = hv.w;
        }
      }
      if (p != 0) {
        const float* wbase = W1A + cb * 32;
        for (int kb = 0; kb < 16; ++kb) {          // rolled; runtime kb only in addrs
          const float4 a4 = *(const float4*)(strip + kb * 4);
          const float* wr = wbase + (size_t)kb * 4 * 128;
#pragma unroll
          for (int c = 0; c < 32; ++c) {
            float v = h1b[c];
            v = fmaf(a4.x, wr[c],       v);
            v = fmaf(a4.y, wr[128 + c], v);
            v = fmaf(a4.z, wr[256 + c], v);
            v = fmaf(a4.w, wr[384 + c], v);
            h1b[c] = v;
          }
        }
      }
#pragma unroll
      for (int c = 0; c < 32; ++c) h1b[c] = fmaxf(h1b[c], 0.f);

      // ---- L2 partial: h2 += h1b @ W2[cb*32 .. +32, :]  (fully static) ----
      const float* w2base = W2 + (size_t)cb * 32 * 64;
#pragma unroll
      for (int k2 = 0; k2 < 32; ++k2) {
        const float hv = h1b[k2];
        const float* wr = w2base + k2 * 64;
#pragma unroll
        for (int c = 0; c < 64; ++c) h2[c] = fmaf(hv, wr[c], h2[c]);
      }
    }

    // ---- h2 = relu(h2 + b2); stage to strip (act is dead) for rolled L3 ----
#pragma unroll
    for (int c = 0; c < 64; ++c) h2[c] = fmaxf(h2[c] + b2[c], 0.f);
#pragma unroll
    for (int i = 0; i < 16; ++i)
      *(float4*)(strip + i * 4) =
          make_float4(h2[i * 4], h2[i * 4 + 1], h2[i * 4 + 2], h2[i * 4 + 3]);

    // ---- L3: logits accumulate into pacc (wo-passes) or pw (with-pass) ----
    if (p < 11) {
      for (int kb = 0; kb < 16; ++kb) {
        const float4 hq = *(const float4*)(strip + kb * 4);
        const float* wr = W3 + (size_t)kb * 4 * 64;
#pragma unroll
        for (int c = 0; c < 64; ++c) {
          float v = pacc[c];
          v = fmaf(hq.x, wr[c],       v);
          v = fmaf(hq.y, wr[64 + c],  v);
          v = fmaf(hq.z, wr[128 + c], v);
          v = fmaf(hq.w, wr[192 + c], v);
          pacc[c] = v;
        }
      }
#pragma unroll
      for (int c = 0; c < 64; ++c) pacc[c] += b3[c];
    } else {
#pragma unroll
      for (int c = 0; c < 64; ++c) pw[c] = b3[c];
      for (int kb = 0; kb < 16; ++kb) {
        const float4 hq = *(const float4*)(strip + kb * 4);
        const float* wr = W3 + (size_t)kb * 4 * 64;
#pragma unroll
        for (int c = 0; c < 64; ++c) {
          float v = pw[c];
          v = fmaf(hq.x, wr[c],       v);
          v = fmaf(hq.y, wr[64 + c],  v);
          v = fmaf(hq.z, wr[128 + c], v);
          v = fmaf(hq.w, wr[192 + c], v);
          pw[c] = v;
        }
      }
    }
  }

  // ---- epilogue: fully lane-local softmax/KL, no shuffles ----
  const float inv11 = 1.0f / 11.0f;
#pragma unroll
  for (int c = 0; c < 64; ++c) pacc[c] *= inv11;
  float mw = pw[0], ma = pacc[0];
#pragma unroll
  for (int c = 1; c < 64; ++c) { mw = fmaxf(mw, pw[c]); ma = fmaxf(ma, pacc[c]); }
  float sw = 0.f, sa = 0.f;
#pragma unroll
  for (int c = 0; c < 64; ++c) { sw += expf(pw[c] - mw); sa += expf(pacc[c] - ma); }
  const float lzw = logf(sw), lza = logf(sa);
  float contrib = 0.f;
#pragma unroll
  for (int c = 0; c < 64; ++c) {
    const float lq = pacc[c] - ma - lza;
    const float lp = pw[c] - mw - lzw;
    contrib += expf(lq) * (lq - lp);
  }
  out[s] = contrib * (1.0f / 64.0f);
}

extern "C" void kernel_launch(void* const* d_in, const int* in_sizes, int n_in,
                              void* d_out, int out_size, void* d_ws, size_t ws_size,
                              hipStream_t stream) {
  (void)in_sizes; (void)n_in; (void)ws_size; (void)out_size;
  const float* obs     = (const float*)d_in[0];
  const float* actions = (const float*)d_in[1];
  const float* W1      = (const float*)d_in[2];
  const float* b1      = (const float*)d_in[3];
  const float* W2      = (const float*)d_in[4];
  const float* b2      = (const float*)d_in[5];
  const float* W3      = (const float*)d_in[6];
  const float* b3      = (const float*)d_in[7];

  // Workspace: HO = obs-part of layer-1 preactivation, 131072 x 128 fp32 = 67.1 MB.
  float* HO = (float*)d_ws;

  TFKeys keys;
  for (unsigned j = 0; j < NCF; ++j) {
    unsigned o0, o1;
    tf2x32(0u, 42u, 0u, j, o0, o1);
    keys.k[2 * j]     = o0;
    keys.k[2 * j + 1] = o1;
  }

  hipLaunchKernelGGL(hobs_kernel, dim3(512), dim3(256), 0, stream,
                     obs, W1, b1, HO);
  hipLaunchKernelGGL(infl2_kernel, dim3(512), dim3(256), 0, stream,
                     actions, W1, W2, b2, W3, b3, HO, (float*)d_out, keys);
}

// Round 2
// 771.500 us; speedup vs baseline: 2.9981x; 2.9981x over previous
//
#include <hip/hip_runtime.h>
#include <cstddef>

#define NCF 10

struct TFKeys { unsigned k[2 * NCF]; };

typedef __attribute__((ext_vector_type(8))) _Float16 f16x8;
typedef __attribute__((ext_vector_type(4))) float f32x4;

// Threefry-2x32, 20 rounds (JAX-compatible, partitionable semantics verified R1).
__host__ __device__ __forceinline__ void tf2x32(unsigned k0, unsigned k1,
                                                unsigned x0, unsigned x1,
                                                unsigned& o0, unsigned& o1) {
  const unsigned ks2 = k0 ^ k1 ^ 0x1BD11BDAu;
  x0 += k0; x1 += k1;
#define TF_R(r) x0 += x1; x1 = (x1 << (r)) | (x1 >> (32 - (r))); x1 ^= x0;
  TF_R(13) TF_R(15) TF_R(26) TF_R(6)
  x0 += k1;  x1 += ks2 + 1u;
  TF_R(17) TF_R(29) TF_R(16) TF_R(24)
  x0 += ks2; x1 += k0 + 2u;
  TF_R(13) TF_R(15) TF_R(26) TF_R(6)
  x0 += k0;  x1 += k1 + 3u;
  TF_R(17) TF_R(29) TF_R(16) TF_R(24)
  x0 += k1;  x1 += ks2 + 4u;
  TF_R(13) TF_R(15) TF_R(26) TF_R(6)
  x0 += ks2; x1 += k0 + 5u;
#undef TF_R
  o0 = x0; o1 = x1;
}

__device__ __forceinline__ float u01(unsigned bits) {
  return __uint_as_float((bits >> 9) | 0x3f800000u) - 1.0f;
}

// fp16x3: x = hi + lo, |x - hi - lo| <= 2^-24 |x|.
__device__ __forceinline__ void split8(const float* v, f16x8& hh, f16x8& ll) {
#pragma unroll
  for (int e = 0; e < 8; ++e) {
    const _Float16 h = (_Float16)v[e];
    hh[e] = h;
    ll[e] = (_Float16)(v[e] - (float)h);
  }
}

// D += Ah*Bh + Ah*Bl + Al*Bh  (drops Al*Bl ~ 2^-24)
#define MFMA3(acc, ah, al, bh, bl)                                          \
  acc = __builtin_amdgcn_mfma_f32_16x16x32_f16(ah, bh, acc, 0, 0, 0);       \
  acc = __builtin_amdgcn_mfma_f32_16x16x32_f16(ah, bl, acc, 0, 0, 0);       \
  acc = __builtin_amdgcn_mfma_f32_16x16x32_f16(al, bh, acc, 0, 0, 0);

// Stage W[K][N] (row-major f32) into hi/lo B-fragment layout:
// frag element ((kt*NTN + nt)*64 + lane)*8 + e  <->  W[kt*32 + (lane>>4)*8 + e][nt*16 + (lane&15)]
template <int K, int N>
__device__ __forceinline__ void stage_frags(const float* __restrict__ W,
                                            _Float16* fh, _Float16* fl, int t) {
  constexpr int NTN = N / 16;
  for (int i = t; i < K * N; i += 512) {
    const int e = i & 7, lane = (i >> 3) & 63, tile = i >> 9;
    const int kt = tile / NTN, nt = tile % NTN;
    const int k = kt * 32 + ((lane >> 4) << 3) + e;
    const int c = nt * 16 + (lane & 15);
    const float w = W[k * N + c];
    const _Float16 h = (_Float16)w;
    fh[i] = h;
    fl[i] = (_Float16)(w - (float)h);
  }
}

// ---------------------------------------------------------------------------
// Kernel 1: HO[s][c] = b1[c] + obs[s][:] @ W1[0:256][c]   (fp16x3 MFMA)
// 1024 blocks x 512 threads; wave owns 16 rows. W1-obs frags in 128KB LDS.
// ---------------------------------------------------------------------------
__global__ __launch_bounds__(512, 1)
void hobs_mfma(const float* __restrict__ obs, const float* __restrict__ W1,
               const float* __restrict__ b1, float* __restrict__ HO) {
  __shared__ __align__(16) _Float16 wh[8 * 8 * 512];   // 64KB
  __shared__ __align__(16) _Float16 wl[8 * 8 * 512];   // 64KB
  const int t = threadIdx.x, wave = t >> 6, lane = t & 63;
  stage_frags<256, 128>(W1, wh, wl, t);
  __syncthreads();

  const int R0 = blockIdx.x * 128 + wave * 16;
  const int cA = lane & 15;            // A row-in-tile / C-D col
  const int kg = (lane >> 4) << 3;     // k base within 32-k tile
  const int r0 = (lane >> 4) << 2;     // C/D row base

  f32x4 acc[8];
#pragma unroll
  for (int nt = 0; nt < 8; ++nt) {
    const float bv = b1[nt * 16 + cA];
    acc[nt] = (f32x4){bv, bv, bv, bv};
  }

  const float* orow = obs + (size_t)(R0 + cA) * 256;
  for (int kt = 0; kt < 8; ++kt) {
    float av[8];
    *(float4*)&av[0] = *(const float4*)(orow + kt * 32 + kg);
    *(float4*)&av[4] = *(const float4*)(orow + kt * 32 + kg + 4);
    f16x8 ah, al;
    split8(av, ah, al);
#pragma unroll
    for (int nt = 0; nt < 8; ++nt) {
      const int tile = kt * 8 + nt;
      const f16x8 bh = *(const f16x8*)&wh[(tile * 64 + lane) * 8];
      const f16x8 bl = *(const f16x8*)&wl[(tile * 64 + lane) * 8];
      MFMA3(acc[nt], ah, al, bh, bl)
    }
  }

#pragma unroll
  for (int nt = 0; nt < 8; ++nt)
#pragma unroll
    for (int j = 0; j < 4; ++j)
      HO[(size_t)(R0 + r0 + j) * 128 + nt * 16 + cA] = acc[nt][j];
}

// ---------------------------------------------------------------------------
// Kernel 2: 12-pass MLP sweep, fp16x3 MFMA. Wave owns 16 samples.
// HO in C-layout regs (L1 acc init); act A-frags generated in registers
// (threefry) or loaded (pass 11); weights as LDS frags; h1/h2 via wave-private
// LDS buffer. Zero barriers in the pass loop. L3 accumulates into pacc frags.
// ---------------------------------------------------------------------------
__global__ __launch_bounds__(512, 2)
void infl_mfma(const float* __restrict__ actions, const float* __restrict__ W1,
               const float* __restrict__ W2, const float* __restrict__ b2,
               const float* __restrict__ W3, const float* __restrict__ b3,
               const float* __restrict__ HO, float* __restrict__ out,
               TFKeys keys) {
  __shared__ __align__(16) _Float16 w1h[8192], w1l[8192];   // 16KB each
  __shared__ __align__(16) _Float16 w2h[8192], w2l[8192];   // 16KB each
  __shared__ __align__(16) _Float16 w3h[4096], w3l[4096];   // 8KB each
  __shared__ __align__(16) float hbuf[8 * 2112];            // 66KB: per-wave h1/h2
  const int t = threadIdx.x, wave = t >> 6, lane = t & 63;

  stage_frags<64, 128>(W1 + 256 * 128, w1h, w1l, t);
  stage_frags<128, 64>(W2, w2h, w2l, t);
  stage_frags<64, 64>(W3, w3h, w3l, t);

  const int R0 = blockIdx.x * 128 + wave * 16;
  const int cA = lane & 15;
  const int kg = (lane >> 4) << 3;
  const int r0 = (lane >> 4) << 2;
  float* hb = &hbuf[wave * 2112];

  float b2r[4], b3r[4];
#pragma unroll
  for (int nt = 0; nt < 4; ++nt) {
    b2r[nt] = b2[nt * 16 + cA];
    b3r[nt] = b3[nt * 16 + cA];
  }

  // HO in C/D layout registers (b1 already folded by kernel 1)
  f32x4 ho[8];
#pragma unroll
  for (int nt = 0; nt < 8; ++nt)
#pragma unroll
    for (int j = 0; j < 4; ++j)
      ho[nt][j] = HO[(size_t)(R0 + r0 + j) * 128 + nt * 16 + cA];

  __syncthreads();   // weight frags ready; only barrier in the kernel

  f32x4 pacc[4], pw[4];
#pragma unroll
  for (int nt = 0; nt < 4; ++nt) {
    pacc[nt] = (f32x4){0.f, 0.f, 0.f, 0.f};
    pw[nt]   = (f32x4){0.f, 0.f, 0.f, 0.f};
  }

  for (int p = 0; p < 12; ++p) {
    // ---- action A-fragments (registers only) ----
    f16x8 ah[2], al[2];
    if (p >= 1 && p <= 10) {
      const unsigned k0 = keys.k[2 * (p - 1)];
      const unsigned k1 = keys.k[2 * (p - 1) + 1];
      const unsigned base = (unsigned)(R0 + cA) * 64u + (unsigned)kg;
#pragma unroll
      for (int kt = 0; kt < 2; ++kt) {
        float v[8];
#pragma unroll
        for (int e = 0; e < 8; ++e) {
          unsigned o0, o1;
          tf2x32(k0, k1, 0u, base + (unsigned)(kt * 32 + e), o0, o1);
          v[e] = u01(o0 ^ o1);
        }
        split8(v, ah[kt], al[kt]);
      }
    } else if (p == 11) {
      const float* arow = actions + (size_t)(R0 + cA) * 64 + kg;
#pragma unroll
      for (int kt = 0; kt < 2; ++kt) {
        float v[8];
        *(float4*)&v[0] = *(const float4*)(arow + kt * 32);
        *(float4*)&v[4] = *(const float4*)(arow + kt * 32 + 4);
        split8(v, ah[kt], al[kt]);
      }
    }

    // ---- L1: h1 = relu(ho + act @ W1a) ----
    f32x4 a1[8];
#pragma unroll
    for (int nt = 0; nt < 8; ++nt) a1[nt] = ho[nt];
    if (p != 0) {
#pragma unroll
      for (int kt = 0; kt < 2; ++kt)
#pragma unroll
        for (int nt = 0; nt < 8; ++nt) {
          const int tile = kt * 8 + nt;
          const f16x8 bh = *(const f16x8*)&w1h[(tile * 64 + lane) * 8];
          const f16x8 bl = *(const f16x8*)&w1l[(tile * 64 + lane) * 8];
          MFMA3(a1[nt], ah[kt], al[kt], bh, bl)
        }
    }
#pragma unroll
    for (int nt = 0; nt < 8; ++nt)
#pragma unroll
      for (int j = 0; j < 4; ++j)
        hb[(r0 + j) * 132 + nt * 16 + cA] = fmaxf(a1[nt][j], 0.f);

    // ---- L2: h2 = relu(h1 @ W2 + b2) ----
    f32x4 a2[4];
#pragma unroll
    for (int nt = 0; nt < 4; ++nt)
      a2[nt] = (f32x4){b2r[nt], b2r[nt], b2r[nt], b2r[nt]};
#pragma unroll
    for (int kt = 0; kt < 4; ++kt) {
      float v[8];
      *(float4*)&v[0] = *(const float4*)&hb[cA * 132 + kt * 32 + kg];
      *(float4*)&v[4] = *(const float4*)&hb[cA * 132 + kt * 32 + kg + 4];
      f16x8 hh, hl;
      split8(v, hh, hl);
#pragma unroll
      for (int nt = 0; nt < 4; ++nt) {
        const int tile = kt * 4 + nt;
        const f16x8 bh = *(const f16x8*)&w2h[(tile * 64 + lane) * 8];
        const f16x8 bl = *(const f16x8*)&w2l[(tile * 64 + lane) * 8];
        MFMA3(a2[nt], hh, hl, bh, bl)
      }
    }
#pragma unroll
    for (int nt = 0; nt < 4; ++nt)
#pragma unroll
      for (int j = 0; j < 4; ++j)
        hb[(r0 + j) * 68 + nt * 16 + cA] = fmaxf(a2[nt][j], 0.f);   // h1 dead: reuse

    // ---- L3: logits into persistent C-frags ----
#pragma unroll
    for (int kt = 0; kt < 2; ++kt) {
      float v[8];
      *(float4*)&v[0] = *(const float4*)&hb[cA * 68 + kt * 32 + kg];
      *(float4*)&v[4] = *(const float4*)&hb[cA * 68 + kt * 32 + kg + 4];
      f16x8 hh, hl;
      split8(v, hh, hl);
      if (p < 11) {
#pragma unroll
        for (int nt = 0; nt < 4; ++nt) {
          const int tile = kt * 4 + nt;
          const f16x8 bh = *(const f16x8*)&w3h[(tile * 64 + lane) * 8];
          const f16x8 bl = *(const f16x8*)&w3l[(tile * 64 + lane) * 8];
          MFMA3(pacc[nt], hh, hl, bh, bl)
        }
      } else {
#pragma unroll
        for (int nt = 0; nt < 4; ++nt) {
          const int tile = kt * 4 + nt;
          const f16x8 bh = *(const f16x8*)&w3h[(tile * 64 + lane) * 8];
          const f16x8 bl = *(const f16x8*)&w3l[(tile * 64 + lane) * 8];
          MFMA3(pw[nt], hh, hl, bh, bl)
        }
      }
    }
  }

  // ---- epilogue: softmax/KL per row, 16-lane shfl reductions ----
  const float inv11 = 1.0f / 11.0f;
#pragma unroll
  for (int j = 0; j < 4; ++j) {
    float pwv[4], pav[4];
#pragma unroll
    for (int nt = 0; nt < 4; ++nt) {
      pwv[nt] = pw[nt][j] + b3r[nt];
      pav[nt] = pacc[nt][j] * inv11 + b3r[nt];
    }
    float mw = fmaxf(fmaxf(pwv[0], pwv[1]), fmaxf(pwv[2], pwv[3]));
    float ma = fmaxf(fmaxf(pav[0], pav[1]), fmaxf(pav[2], pav[3]));
#pragma unroll
    for (int off = 1; off < 16; off <<= 1) {
      mw = fmaxf(mw, __shfl_xor(mw, off, 64));
      ma = fmaxf(ma, __shfl_xor(ma, off, 64));
    }
    float sw = 0.f, sa = 0.f;
#pragma unroll
    for (int nt = 0; nt < 4; ++nt) {
      sw += expf(pwv[nt] - mw);
      sa += expf(pav[nt] - ma);
    }
#pragma unroll
    for (int off = 1; off < 16; off <<= 1) {
      sw += __shfl_xor(sw, off, 64);
      sa += __shfl_xor(sa, off, 64);
    }
    const float lzw = logf(sw), lza = logf(sa);
    float contrib = 0.f;
#pragma unroll
    for (int nt = 0; nt < 4; ++nt) {
      const float lq = pav[nt] - ma - lza;
      const float lp = pwv[nt] - mw - lzw;
      contrib += expf(lq) * (lq - lp);
    }
#pragma unroll
    for (int off = 1; off < 16; off <<= 1)
      contrib += __shfl_xor(contrib, off, 64);
    if (cA == 0) out[R0 + r0 + j] = contrib * (1.0f / 64.0f);
  }
}

extern "C" void kernel_launch(void* const* d_in, const int* in_sizes, int n_in,
                              void* d_out, int out_size, void* d_ws, size_t ws_size,
                              hipStream_t stream) {
  (void)in_sizes; (void)n_in; (void)ws_size; (void)out_size;
  const float* obs     = (const float*)d_in[0];
  const float* actions = (const float*)d_in[1];
  const float* W1      = (const float*)d_in[2];
  const float* b1      = (const float*)d_in[3];
  const float* W2      = (const float*)d_in[4];
  const float* b2      = (const float*)d_in[5];
  const float* W3      = (const float*)d_in[6];
  const float* b3      = (const float*)d_in[7];

  // Workspace: HO = obs-part of layer-1 preactivation (+b1), 131072 x 128 fp32.
  float* HO = (float*)d_ws;

  TFKeys keys;
  for (unsigned j = 0; j < NCF; ++j) {
    unsigned o0, o1;
    tf2x32(0u, 42u, 0u, j, o0, o1);
    keys.k[2 * j]     = o0;
    keys.k[2 * j + 1] = o1;
  }

  hipLaunchKernelGGL(hobs_mfma, dim3(1024), dim3(512), 0, stream,
                     obs, W1, b1, HO);
  hipLaunchKernelGGL(infl_mfma, dim3(1024), dim3(512), 0, stream,
                     actions, W1, W2, b2, W3, b3, HO, (float*)d_out, keys);
}

// Round 3
// 594.493 us; speedup vs baseline: 3.8907x; 1.2977x over previous
//
#include <hip/hip_runtime.h>
#include <cstddef>

#define NCF 10

struct TFKeys { unsigned k[2 * NCF]; };

typedef __attribute__((ext_vector_type(8))) _Float16 f16x8;
typedef __attribute__((ext_vector_type(4))) float f32x4;

// Threefry-2x32, 20 rounds (JAX-compatible, partitionable semantics verified R1).
__host__ __device__ __forceinline__ void tf2x32(unsigned k0, unsigned k1,
                                                unsigned x0, unsigned x1,
                                                unsigned& o0, unsigned& o1) {
  const unsigned ks2 = k0 ^ k1 ^ 0x1BD11BDAu;
  x0 += k0; x1 += k1;
#define TF_R(r) x0 += x1; x1 = (x1 << (r)) | (x1 >> (32 - (r))); x1 ^= x0;
  TF_R(13) TF_R(15) TF_R(26) TF_R(6)
  x0 += k1;  x1 += ks2 + 1u;
  TF_R(17) TF_R(29) TF_R(16) TF_R(24)
  x0 += ks2; x1 += k0 + 2u;
  TF_R(13) TF_R(15) TF_R(26) TF_R(6)
  x0 += k0;  x1 += k1 + 3u;
  TF_R(17) TF_R(29) TF_R(16) TF_R(24)
  x0 += k1;  x1 += ks2 + 4u;
  TF_R(13) TF_R(15) TF_R(26) TF_R(6)
  x0 += ks2; x1 += k0 + 5u;
#undef TF_R
  o0 = x0; o1 = x1;
}

__device__ __forceinline__ float u01(unsigned bits) {
  return __uint_as_float((bits >> 9) | 0x3f800000u) - 1.0f;
}

// fp16x3 split of 8 floats: x = hi + lo, |x - hi - lo| <= 2^-24 |x|.
__device__ __forceinline__ void split44(const float4 a, const float4 b,
                                        f16x8& hh, f16x8& ll) {
  const float v[8] = {a.x, a.y, a.z, a.w, b.x, b.y, b.z, b.w};
#pragma unroll
  for (int e = 0; e < 8; ++e) {
    const _Float16 h = (_Float16)v[e];
    hh[e] = h;
    ll[e] = (_Float16)(v[e] - (float)h);
  }
}

// D += Ah*Bh + Ah*Bl + Al*Bh  (drops Al*Bl ~ 2^-24)
#define MFMA3(acc, ah, al, bh, bl)                                          \
  acc = __builtin_amdgcn_mfma_f32_16x16x32_f16(ah, bh, acc, 0, 0, 0);       \
  acc = __builtin_amdgcn_mfma_f32_16x16x32_f16(ah, bl, acc, 0, 0, 0);       \
  acc = __builtin_amdgcn_mfma_f32_16x16x32_f16(al, bh, acc, 0, 0, 0);

// Stage W[K][N] (row-major f32) into hi/lo B-fragment layout (verified R2):
// frag elem ((kt*NTN+nt)*64+lane)*8+e  <->  W[kt*32+(lane>>4)*8+e][nt*16+(lane&15)]
template <int K, int N>
__device__ __forceinline__ void stage_frags(const float* __restrict__ W,
                                            _Float16* fh, _Float16* fl, int t) {
  constexpr int NTN = N / 16;
  for (int i = t; i < K * N; i += 512) {
    const int e = i & 7, lane = (i >> 3) & 63, tile = i >> 9;
    const int kt = tile / NTN, nt = tile % NTN;
    const int k = kt * 32 + ((lane >> 4) << 3) + e;
    const int c = nt * 16 + (lane & 15);
    const float w = W[k * N + c];
    const _Float16 h = (_Float16)w;
    fh[i] = h;
    fl[i] = (_Float16)(w - (float)h);
  }
}

// ---------------------------------------------------------------------------
// Fused kernel: per-block HO prologue (W1-obs frags in barrier-aliased LDS),
// then 12-pass MLP sweep. Wave owns 16 samples; ho/pacc in registers; pass 11
// peeled so pw's live range is the tail only. waves_per_eu(2,2): LDS already
// caps at 1 block/CU (2 waves/SIMD) -> grant 256 VGPRs, eliminate spills.
// ---------------------------------------------------------------------------
__global__ __launch_bounds__(512, 2) __attribute__((amdgpu_waves_per_eu(2, 2)))
void infl_fused(const float* __restrict__ obs, const float* __restrict__ actions,
                const float* __restrict__ W1, const float* __restrict__ b1,
                const float* __restrict__ W2, const float* __restrict__ b2,
                const float* __restrict__ W3, const float* __restrict__ b3,
                float* __restrict__ out, TFKeys keys) {
  // 149504 B. Prologue: [0,131072) = W1-obs hi/lo frags.
  // Pass loop:  [0,81920) = pass-weight frags, [81920,149504) = per-wave hbuf.
  __shared__ __align__(16) unsigned char smem[149504];
  _Float16* w1oh = (_Float16*)smem;                   // 256x128 hi (64KB)
  _Float16* w1ol = (_Float16*)(smem + 65536);         // 256x128 lo (64KB)
  _Float16* w1h  = (_Float16*)smem;                   // W1-act 64x128 hi
  _Float16* w1l  = (_Float16*)(smem + 16384);
  _Float16* w2h  = (_Float16*)(smem + 32768);         // W2 128x64 hi
  _Float16* w2l  = (_Float16*)(smem + 49152);
  _Float16* w3h  = (_Float16*)(smem + 65536);         // W3 64x64 hi
  _Float16* w3l  = (_Float16*)(smem + 73728);
  float*    hbuf = (float*)(smem + 81920);            // 8 x 2112 f32

  const int t = threadIdx.x, wave = t >> 6, lane = t & 63;
  const int R0 = blockIdx.x * 128 + wave * 16;
  const int cA = lane & 15;            // A-row / C-D col
  const int kg = (lane >> 4) << 3;     // k base within 32-k tile
  const int r0 = (lane >> 4) << 2;     // C/D row base
  float* hb = hbuf + wave * 2112;

  // ================= prologue: ho = b1 + obs @ W1[0:256] ==================
  stage_frags<256, 128>(W1, w1oh, w1ol, t);
  __syncthreads();

  f32x4 ho[8];
#pragma unroll
  for (int nt = 0; nt < 8; ++nt) {
    const float bv = b1[nt * 16 + cA];
    ho[nt] = (f32x4){bv, bv, bv, bv};
  }
  {
    const float* orow = obs + (size_t)(R0 + cA) * 256;
    float4 ov[16];
#pragma unroll
    for (int kt = 0; kt < 8; ++kt) {
      ov[2 * kt]     = *(const float4*)(orow + kt * 32 + kg);
      ov[2 * kt + 1] = *(const float4*)(orow + kt * 32 + kg + 4);
    }
#pragma unroll
    for (int kt = 0; kt < 8; ++kt) {
      f16x8 ah, al;
      split44(ov[2 * kt], ov[2 * kt + 1], ah, al);
#pragma unroll
      for (int nt = 0; nt < 8; ++nt) {
        const int tile = kt * 8 + nt;
        const f16x8 bh = *(const f16x8*)&w1oh[(tile * 64 + lane) * 8];
        const f16x8 bl = *(const f16x8*)&w1ol[(tile * 64 + lane) * 8];
        MFMA3(ho[nt], ah, al, bh, bl)
      }
    }
  }
  __syncthreads();   // prologue reads done; re-stage pass weights

  stage_frags<64, 128>(W1 + 256 * 128, w1h, w1l, t);
  stage_frags<128, 64>(W2, w2h, w2l, t);
  stage_frags<64, 64>(W3, w3h, w3l, t);

  float b2r[4], b3r[4];
#pragma unroll
  for (int nt = 0; nt < 4; ++nt) {
    b2r[nt] = b2[nt * 16 + cA];
    b3r[nt] = b3[nt * 16 + cA];
  }
  __syncthreads();   // last barrier of the kernel

  // ======================== MLP body (one pass) ===========================
  // L1: a1 = ho (+ act @ W1a); relu -> hb[16][132]
  // L2: h2 = relu(h1 @ W2 + b2) -> hb[16][68] (h1 dead)
  // L3: acc3 += h2 @ W3
#define MLP_BODY(HAS_ACT, acc3)                                              \
  {                                                                          \
    f32x4 a1[8];                                                             \
    _Pragma("unroll") for (int nt = 0; nt < 8; ++nt) a1[nt] = ho[nt];        \
    if (HAS_ACT) {                                                           \
      _Pragma("unroll") for (int kt = 0; kt < 2; ++kt)                       \
      _Pragma("unroll") for (int nt = 0; nt < 8; ++nt) {                     \
        const int tile = kt * 8 + nt;                                        \
        const f16x8 bh = *(const f16x8*)&w1h[(tile * 64 + lane) * 8];        \
        const f16x8 bl = *(const f16x8*)&w1l[(tile * 64 + lane) * 8];        \
        MFMA3(a1[nt], ah[kt], al[kt], bh, bl)                                \
      }                                                                      \
    }                                                                        \
    _Pragma("unroll") for (int nt = 0; nt < 8; ++nt)                         \
    _Pragma("unroll") for (int j = 0; j < 4; ++j)                            \
      hb[(r0 + j) * 132 + nt * 16 + cA] = fmaxf(a1[nt][j], 0.f);             \
    f32x4 a2[4];                                                             \
    _Pragma("unroll") for (int nt = 0; nt < 4; ++nt)                         \
      a2[nt] = (f32x4){b2r[nt], b2r[nt], b2r[nt], b2r[nt]};                  \
    _Pragma("unroll") for (int kt = 0; kt < 4; ++kt) {                       \
      const float4 va = *(const float4*)&hb[cA * 132 + kt * 32 + kg];        \
      const float4 vb = *(const float4*)&hb[cA * 132 + kt * 32 + kg + 4];    \
      f16x8 hh, hl;                                                          \
      split44(va, vb, hh, hl);                                               \
      _Pragma("unroll") for (int nt = 0; nt < 4; ++nt) {                     \
        const int tile = kt * 4 + nt;                                        \
        const f16x8 bh = *(const f16x8*)&w2h[(tile * 64 + lane) * 8];        \
        const f16x8 bl = *(const f16x8*)&w2l[(tile * 64 + lane) * 8];        \
        MFMA3(a2[nt], hh, hl, bh, bl)                                        \
      }                                                                      \
    }                                                                        \
    _Pragma("unroll") for (int nt = 0; nt < 4; ++nt)                         \
    _Pragma("unroll") for (int j = 0; j < 4; ++j)                            \
      hb[(r0 + j) * 68 + nt * 16 + cA] = fmaxf(a2[nt][j], 0.f);              \
    _Pragma("unroll") for (int kt = 0; kt < 2; ++kt) {                       \
      const float4 va = *(const float4*)&hb[cA * 68 + kt * 32 + kg];         \
      const float4 vb = *(const float4*)&hb[cA * 68 + kt * 32 + kg + 4];     \
      f16x8 hh, hl;                                                          \
      split44(va, vb, hh, hl);                                               \
      _Pragma("unroll") for (int nt = 0; nt < 4; ++nt) {                     \
        const int tile = kt * 4 + nt;                                        \
        const f16x8 bh = *(const f16x8*)&w3h[(tile * 64 + lane) * 8];        \
        const f16x8 bl = *(const f16x8*)&w3l[(tile * 64 + lane) * 8];        \
        MFMA3(acc3[nt], hh, hl, bh, bl)                                      \
      }                                                                      \
    }                                                                        \
  }

  f32x4 pacc[4];
#pragma unroll
  for (int nt = 0; nt < 4; ++nt) pacc[nt] = (f32x4){0.f, 0.f, 0.f, 0.f};

  // ---- passes 0..10 -> pacc (p=0: zero actions, L1a skipped) ----
  for (int p = 0; p < 11; ++p) {
    f16x8 ah[2], al[2];
    if (p >= 1) {
      const unsigned k0 = keys.k[2 * (p - 1)];
      const unsigned k1 = keys.k[2 * (p - 1) + 1];
      const unsigned base = (unsigned)(R0 + cA) * 64u + (unsigned)kg;
#pragma unroll
      for (int kt = 0; kt < 2; ++kt) {
        float v[8];
#pragma unroll
        for (int e = 0; e < 8; ++e) {
          unsigned o0, o1;
          tf2x32(k0, k1, 0u, base + (unsigned)(kt * 32 + e), o0, o1);
          v[e] = u01(o0 ^ o1);
        }
        split44(*(const float4*)&v[0], *(const float4*)&v[4], ah[kt], al[kt]);
      }
    }
    MLP_BODY(p != 0, pacc)
  }

  // ---- peeled with-actions pass -> pw (short live range) ----
  f32x4 pw[4];
#pragma unroll
  for (int nt = 0; nt < 4; ++nt) pw[nt] = (f32x4){0.f, 0.f, 0.f, 0.f};
  {
    f16x8 ah[2], al[2];
    const float* arow = actions + (size_t)(R0 + cA) * 64 + kg;
#pragma unroll
    for (int kt = 0; kt < 2; ++kt) {
      const float4 va = *(const float4*)(arow + kt * 32);
      const float4 vb = *(const float4*)(arow + kt * 32 + 4);
      split44(va, vb, ah[kt], al[kt]);
    }
    MLP_BODY(true, pw)
  }

  // ---- epilogue: softmax/KL per row, 16-lane shfl reductions ----
  const float inv11 = 1.0f / 11.0f;
#pragma unroll
  for (int j = 0; j < 4; ++j) {
    float pwv[4], pav[4];
#pragma unroll
    for (int nt = 0; nt < 4; ++nt) {
      pwv[nt] = pw[nt][j] + b3r[nt];
      pav[nt] = pacc[nt][j] * inv11 + b3r[nt];
    }
    float mw = fmaxf(fmaxf(pwv[0], pwv[1]), fmaxf(pwv[2], pwv[3]));
    float ma = fmaxf(fmaxf(pav[0], pav[1]), fmaxf(pav[2], pav[3]));
#pragma unroll
    for (int off = 1; off < 16; off <<= 1) {
      mw = fmaxf(mw, __shfl_xor(mw, off, 64));
      ma = fmaxf(ma, __shfl_xor(ma, off, 64));
    }
    float sw = 0.f, sa = 0.f;
#pragma unroll
    for (int nt = 0; nt < 4; ++nt) {
      sw += expf(pwv[nt] - mw);
      sa += expf(pav[nt] - ma);
    }
#pragma unroll
    for (int off = 1; off < 16; off <<= 1) {
      sw += __shfl_xor(sw, off, 64);
      sa += __shfl_xor(sa, off, 64);
    }
    const float lzw = logf(sw), lza = logf(sa);
    float contrib = 0.f;
#pragma unroll
    for (int nt = 0; nt < 4; ++nt) {
      const float lq = pav[nt] - ma - lza;
      const float lp = pwv[nt] - mw - lzw;
      contrib += expf(lq) * (lq - lp);
    }
#pragma unroll
    for (int off = 1; off < 16; off <<= 1)
      contrib += __shfl_xor(contrib, off, 64);
    if (cA == 0) out[R0 + r0 + j] = contrib * (1.0f / 64.0f);
  }
}

extern "C" void kernel_launch(void* const* d_in, const int* in_sizes, int n_in,
                              void* d_out, int out_size, void* d_ws, size_t ws_size,
                              hipStream_t stream) {
  (void)in_sizes; (void)n_in; (void)d_ws; (void)ws_size; (void)out_size;
  const float* obs     = (const float*)d_in[0];
  const float* actions = (const float*)d_in[1];
  const float* W1      = (const float*)d_in[2];
  const float* b1      = (const float*)d_in[3];
  const float* W2      = (const float*)d_in[4];
  const float* b2      = (const float*)d_in[5];
  const float* W3      = (const float*)d_in[6];
  const float* b3      = (const float*)d_in[7];

  TFKeys keys;
  for (unsigned j = 0; j < NCF; ++j) {
    unsigned o0, o1;
    tf2x32(0u, 42u, 0u, j, o0, o1);
    keys.k[2 * j]     = o0;
    keys.k[2 * j + 1] = o1;
  }

  hipLaunchKernelGGL(infl_fused, dim3(1024), dim3(512), 0, stream,
                     obs, actions, W1, b1, W2, b2, W3, b3, (float*)d_out, keys);
}